// Round 4
// baseline (7048.370 us; speedup 1.0000x reference)
//
#include <hip/hip_runtime.h>
#include <hip/hip_bf16.h>

// ---------------------------------------------------------------------------
// HAT block: window MSA (+RPE) -> MLP -> overlapping cross-attention -> blend
// B=4, C=192, H=W=256, WS=8, OV=2, NH=8, HD=24
// Round 3: bf16-at-rest intermediates (fp32 math), aliased workspace 576 MiB,
//          ws_size guard (insufficient ws -> clean no-op, absmax ~10.9 signal).
// ---------------------------------------------------------------------------

#define NWIN   4096        // 4 * 32 * 32 windows
#define NTOK   262144      // NWIN * 64 tokens
#define SCALEA 0.20412414523193154f   // 24^-0.5

typedef unsigned short u16;
typedef unsigned int   u32;

static __device__ __forceinline__ float bfbits(u32 v) {
    return __uint_as_float(v << 16);
}
static __device__ __forceinline__ u16 fbits(float f) {
    __hip_bfloat16 h = __float2bfloat16(f);   // RNE
    return *reinterpret_cast<u16*>(&h);
}
static __device__ __forceinline__ u32 pack2(float a, float b) {
    return (u32)fbits(a) | ((u32)fbits(b) << 16);
}
static __device__ __forceinline__ void unpack8(uint4 u, float* d) {
    d[0] = bfbits(u.x & 0xffff); d[1] = bfbits(u.x >> 16);
    d[2] = bfbits(u.y & 0xffff); d[3] = bfbits(u.y >> 16);
    d[4] = bfbits(u.z & 0xffff); d[5] = bfbits(u.z >> 16);
    d[6] = bfbits(u.w & 0xffff); d[7] = bfbits(u.w >> 16);
}

// ---- partition: x (B,C,H,W) fp32 -> xw (win, n, c) bf16 --------------------
__global__ __launch_bounds__(256) void k_part(const float* __restrict__ x,
                                              u16* __restrict__ xw) {
    __shared__ float tile[192][65];
    int win = blockIdx.x;
    int b = win >> 10, wh = (win >> 5) & 31, ww = win & 31;
    int t = threadIdx.x;
    const float* xb = x + (size_t)b * 192 * 65536 + (size_t)(wh * 8) * 256 + ww * 8;
    for (int id = t; id < 12288; id += 256) {
        int c = id >> 6, pix = id & 63;
        tile[c][pix] = xb[(size_t)c * 65536 + (pix >> 3) * 256 + (pix & 7)];
    }
    __syncthreads();
    u16* ow = xw + (size_t)win * 12288;
    for (int id = t; id < 12288; id += 256) {
        int n = id / 192, c = id - n * 192;
        ow[id] = fbits(tile[c][n]);
    }
}

// ---- LayerNorm over 192 channels (bf16 in/out, fp32 math) ------------------
__global__ __launch_bounds__(256) void k_ln(const u16* __restrict__ in,
                                            const float* __restrict__ g,
                                            const float* __restrict__ bb,
                                            u16* __restrict__ out) {
    int wid = threadIdx.x >> 6, lane = threadIdx.x & 63;
    size_t tok = (size_t)blockIdx.x * 4 + wid;
    const u16* p = in + tok * 192;
    float x0 = bfbits(p[lane]), x1 = bfbits(p[lane + 64]), x2 = bfbits(p[lane + 128]);
    float s  = x0 + x1 + x2;
    float s2 = x0 * x0 + x1 * x1 + x2 * x2;
#pragma unroll
    for (int off = 32; off; off >>= 1) {
        s  += __shfl_xor(s, off);
        s2 += __shfl_xor(s2, off);
    }
    float mean = s * (1.f / 192.f);
    float var  = s2 * (1.f / 192.f) - mean * mean;
    float rstd = rsqrtf(var + 1e-5f);
    u16* o = out + tok * 192;
    o[lane]       = fbits((x0 - mean) * rstd * g[lane]       + bb[lane]);
    o[lane + 64]  = fbits((x1 - mean) * rstd * g[lane + 64]  + bb[lane + 64]);
    o[lane + 128] = fbits((x2 - mean) * rstd * g[lane + 128] + bb[lane + 128]);
}

// ---- GEMM: C(MxN) bf16 = A(MxK) @ B(KxN)fp32 [+ Res bf16] ------------------
// 64x64 block tile, BK=16, 256 threads, 4x4 per thread, fp32 math.
// GATHER=0: A is bf16 row-major. GATHER=1: A rows gathered from fp32 x
//           (B,C,H,W), token m -> (b = m>>16, pix = m&65535), stride 65536/ch.
template <int GATHER>
__global__ __launch_bounds__(256) void k_gemm(const void* __restrict__ Av,
                                              const float* __restrict__ Bw,
                                              u16* __restrict__ C,
                                              const u16* __restrict__ Res,
                                              int M, int N, int K) {
    __shared__ float As[16][64];
    __shared__ float Bs[16][64];
    __shared__ long long abase[64];
    int m0 = blockIdx.x << 6, n0 = blockIdx.y << 6;
    int t = threadIdx.x, tx = t & 15, ty = t >> 4;

    if (GATHER) {
        if (t < 64) {
            int m = m0 + t;
            int b = m >> 16, pix = m & 65535;
            abase[t] = (long long)b * (192 * 65536) + pix;
        }
        __syncthreads();
    }

    float acc[4][4] = {};
    int ra = t >> 2, ka = (t & 3) << 2;     // A tile: row ra, k ka..ka+3
    int kb = t >> 4, nb = (t & 15) << 2;    // B tile: k kb, col nb..nb+3
    const u16*   Ab = (const u16*)Av;
    const float* Af = (const float*)Av;

    for (int k0 = 0; k0 < K; k0 += 16) {
        if (!GATHER) {
            uint2 a2 = *(const uint2*)(Ab + (size_t)(m0 + ra) * K + (k0 + ka));
            As[ka][ra]     = bfbits(a2.x & 0xffff);
            As[ka + 1][ra] = bfbits(a2.x >> 16);
            As[ka + 2][ra] = bfbits(a2.y & 0xffff);
            As[ka + 3][ra] = bfbits(a2.y >> 16);
        } else {
            long long base = abase[ra];
#pragma unroll
            for (int u = 0; u < 4; ++u)
                As[ka + u][ra] = Af[base + (size_t)(k0 + ka + u) * 65536];
        }
        *(float4*)&Bs[kb][nb] = *(const float4*)(Bw + (size_t)(k0 + kb) * N + (n0 + nb));
        __syncthreads();
#pragma unroll
        for (int k = 0; k < 16; ++k) {
            float4 a4 = *(const float4*)&As[k][ty << 2];
            float4 b4 = *(const float4*)&Bs[k][tx << 2];
            float av[4] = {a4.x, a4.y, a4.z, a4.w};
            float bv[4] = {b4.x, b4.y, b4.z, b4.w};
#pragma unroll
            for (int i = 0; i < 4; ++i)
#pragma unroll
                for (int j = 0; j < 4; ++j)
                    acc[i][j] = fmaf(av[i], bv[j], acc[i][j]);
        }
        __syncthreads();
    }

#pragma unroll
    for (int i = 0; i < 4; ++i) {
        int row = m0 + (ty << 2) + i;
        size_t co = (size_t)row * N + n0 + (tx << 2);
        float v[4] = {acc[i][0], acc[i][1], acc[i][2], acc[i][3]};
        if (Res) {
            uint2 r2 = *(const uint2*)(Res + co);
            v[0] += bfbits(r2.x & 0xffff); v[1] += bfbits(r2.x >> 16);
            v[2] += bfbits(r2.y & 0xffff); v[3] += bfbits(r2.y >> 16);
        }
        uint2 st;
        st.x = pack2(v[0], v[1]);
        st.y = pack2(v[2], v[3]);
        *(uint2*)(C + co) = st;
    }
}

// ---- W-MSA attention: one wave per (window, head), online softmax ----------
__global__ __launch_bounds__(64) void k_wattn(const u16* __restrict__ qkv,
                                              const float* __restrict__ rpe,
                                              u16* __restrict__ out) {
    __shared__ float ks[64][28], vs[64][28];
    int win = blockIdx.x >> 3, head = blockIdx.x & 7;
    int lane = threadIdx.x;
    const u16* base = qkv + ((size_t)win * 64 + lane) * 576 + head * 24;
    float q[24];
    unpack8(*(const uint4*)(base + 0),  q + 0);
    unpack8(*(const uint4*)(base + 8),  q + 8);
    unpack8(*(const uint4*)(base + 16), q + 16);
    unpack8(*(const uint4*)(base + 192), &ks[lane][0]);
    unpack8(*(const uint4*)(base + 200), &ks[lane][8]);
    unpack8(*(const uint4*)(base + 208), &ks[lane][16]);
    unpack8(*(const uint4*)(base + 384), &vs[lane][0]);
    unpack8(*(const uint4*)(base + 392), &vs[lane][8]);
    unpack8(*(const uint4*)(base + 400), &vs[lane][16]);
    __syncthreads();
    int my = lane >> 3, mx = lane & 7;
    float m = -1e30f, l = 0.f, o[24] = {};
    for (int j = 0; j < 64; ++j) {
        const float4* kr = (const float4*)ks[j];
        float acc = 0.f;
#pragma unroll
        for (int u = 0; u < 6; ++u) {
            float4 k4 = kr[u];
            acc = fmaf(q[u * 4 + 0], k4.x, acc);
            acc = fmaf(q[u * 4 + 1], k4.y, acc);
            acc = fmaf(q[u * 4 + 2], k4.z, acc);
            acc = fmaf(q[u * 4 + 3], k4.w, acc);
        }
        int jy = j >> 3, jx = j & 7;
        int idx = (my - jy + 7) * 15 + (mx - jx + 7);
        float sv = acc * SCALEA + rpe[idx * 8 + head];
        float mn = fmaxf(m, sv);
        float corr = expf(m - mn);
        float p = expf(sv - mn);
        l = l * corr + p;
        const float4* vr = (const float4*)vs[j];
#pragma unroll
        for (int u = 0; u < 6; ++u) {
            float4 v4 = vr[u];
            o[u * 4 + 0] = o[u * 4 + 0] * corr + p * v4.x;
            o[u * 4 + 1] = o[u * 4 + 1] * corr + p * v4.y;
            o[u * 4 + 2] = o[u * 4 + 2] * corr + p * v4.z;
            o[u * 4 + 3] = o[u * 4 + 3] * corr + p * v4.w;
        }
        m = mn;
    }
    float inv = 1.f / l;
    u16* op = out + ((size_t)win * 64 + lane) * 192 + head * 24;
    uint4 s0, s1, s2;
    s0.x = pack2(o[0] * inv, o[1] * inv);   s0.y = pack2(o[2] * inv, o[3] * inv);
    s0.z = pack2(o[4] * inv, o[5] * inv);   s0.w = pack2(o[6] * inv, o[7] * inv);
    s1.x = pack2(o[8] * inv, o[9] * inv);   s1.y = pack2(o[10] * inv, o[11] * inv);
    s1.z = pack2(o[12] * inv, o[13] * inv); s1.w = pack2(o[14] * inv, o[15] * inv);
    s2.x = pack2(o[16] * inv, o[17] * inv); s2.y = pack2(o[18] * inv, o[19] * inv);
    s2.z = pack2(o[20] * inv, o[21] * inv); s2.w = pack2(o[22] * inv, o[23] * inv);
    *(uint4*)(op + 0)  = s0;
    *(uint4*)(op + 8)  = s1;
    *(uint4*)(op + 16) = s2;
}

// ---- OCA attention: one wave per (window, head); K/V gathered with reflect -
__global__ __launch_bounds__(64) void k_oattn(const u16* __restrict__ qb,
                                              const u16* __restrict__ kvp,
                                              u16* __restrict__ out) {
    __shared__ float ks[144][28], vs[144][28];
    int win = blockIdx.x >> 3, head = blockIdx.x & 7;
    int lane = threadIdx.x;
    int b = win >> 10, wh = (win >> 5) & 31, ww = win & 31;
    for (int j = lane; j < 144; j += 64) {
        int rr = j / 12, cc = j - rr * 12;
        int h = wh * 8 - 2 + rr; h = h < 0 ? -h : (h > 255 ? 510 - h : h);
        int w = ww * 8 - 2 + cc; w = w < 0 ? -w : (w > 255 ? 510 - w : w);
        const u16* bp = kvp + ((size_t)(b << 16) + h * 256 + w) * 384 + head * 24;
        unpack8(*(const uint4*)(bp + 0),   &ks[j][0]);
        unpack8(*(const uint4*)(bp + 8),   &ks[j][8]);
        unpack8(*(const uint4*)(bp + 16),  &ks[j][16]);
        unpack8(*(const uint4*)(bp + 192), &vs[j][0]);
        unpack8(*(const uint4*)(bp + 200), &vs[j][8]);
        unpack8(*(const uint4*)(bp + 208), &vs[j][16]);
    }
    float q[24];
    const u16* qp = qb + ((size_t)win * 64 + lane) * 192 + head * 24;
    unpack8(*(const uint4*)(qp + 0),  q + 0);
    unpack8(*(const uint4*)(qp + 8),  q + 8);
    unpack8(*(const uint4*)(qp + 16), q + 16);
    __syncthreads();
    float m = -1e30f, l = 0.f, o[24] = {};
    for (int j = 0; j < 144; ++j) {
        const float4* kr = (const float4*)ks[j];
        float acc = 0.f;
#pragma unroll
        for (int u = 0; u < 6; ++u) {
            float4 k4 = kr[u];
            acc = fmaf(q[u * 4 + 0], k4.x, acc);
            acc = fmaf(q[u * 4 + 1], k4.y, acc);
            acc = fmaf(q[u * 4 + 2], k4.z, acc);
            acc = fmaf(q[u * 4 + 3], k4.w, acc);
        }
        float sv = acc * SCALEA;
        float mn = fmaxf(m, sv);
        float corr = expf(m - mn);
        float p = expf(sv - mn);
        l = l * corr + p;
        const float4* vr = (const float4*)vs[j];
#pragma unroll
        for (int u = 0; u < 6; ++u) {
            float4 v4 = vr[u];
            o[u * 4 + 0] = o[u * 4 + 0] * corr + p * v4.x;
            o[u * 4 + 1] = o[u * 4 + 1] * corr + p * v4.y;
            o[u * 4 + 2] = o[u * 4 + 2] * corr + p * v4.z;
            o[u * 4 + 3] = o[u * 4 + 3] * corr + p * v4.w;
        }
        m = mn;
    }
    float inv = 1.f / l;
    u16* op = out + ((size_t)win * 64 + lane) * 192 + head * 24;
    uint4 s0, s1, s2;
    s0.x = pack2(o[0] * inv, o[1] * inv);   s0.y = pack2(o[2] * inv, o[3] * inv);
    s0.z = pack2(o[4] * inv, o[5] * inv);   s0.w = pack2(o[6] * inv, o[7] * inv);
    s1.x = pack2(o[8] * inv, o[9] * inv);   s1.y = pack2(o[10] * inv, o[11] * inv);
    s1.z = pack2(o[12] * inv, o[13] * inv); s1.w = pack2(o[14] * inv, o[15] * inv);
    s2.x = pack2(o[16] * inv, o[17] * inv); s2.y = pack2(o[18] * inv, o[19] * inv);
    s2.z = pack2(o[20] * inv, o[21] * inv); s2.w = pack2(o[22] * inv, o[23] * inv);
    *(uint4*)(op + 0)  = s0;
    *(uint4*)(op + 8)  = s1;
    *(uint4*)(op + 16) = s2;
}

// ---- exact GELU in-place on bf16, 8 elems/thread ---------------------------
__global__ __launch_bounds__(256) void k_gelu(u16* __restrict__ p, long long n8) {
    for (long long i = (long long)blockIdx.x * 256 + threadIdx.x; i < n8;
         i += (long long)gridDim.x * 256) {
        uint4 u = *(uint4*)(p + i * 8);
        float d[8];
        unpack8(u, d);
#pragma unroll
        for (int j = 0; j < 8; ++j)
            d[j] = 0.5f * d[j] * (1.f + erff(d[j] * 0.70710678118654752f));
        u.x = pack2(d[0], d[1]); u.y = pack2(d[2], d[3]);
        u.z = pack2(d[4], d[5]); u.w = pack2(d[6], d[7]);
        *(uint4*)(p + i * 8) = u;
    }
}

// ---- final blend: out = x + a*y_win + (1-a)*oca (reverse partition) --------
__global__ __launch_bounds__(256) void k_combine(const float* __restrict__ x,
                                                 const u16* __restrict__ y,
                                                 const u16* __restrict__ oca,
                                                 const float* __restrict__ alpha_p,
                                                 float* __restrict__ out) {
    float a = alpha_p[0];
    for (size_t idx = (size_t)blockIdx.x * 256 + threadIdx.x; idx < 50331648ull;
         idx += (size_t)gridDim.x * 256) {
        int w = idx & 255;
        int h = (int)(idx >> 8) & 255;
        int bc = (int)(idx >> 16);          // b*192 + c
        int c = bc % 192, b = bc / 192;
        int win = (b * 32 + (h >> 3)) * 32 + (w >> 3);
        int n = ((h & 7) << 3) + (w & 7);
        size_t off = ((size_t)win * 64 + n) * 192 + c;
        out[idx] = x[idx] + a * bfbits(y[off]) + (1.f - a) * bfbits(oca[off]);
    }
}

// ---------------------------------------------------------------------------
extern "C" void kernel_launch(void* const* d_in, const int* in_sizes, int n_in,
                              void* d_out, int out_size, void* d_ws, size_t ws_size,
                              hipStream_t stream) {
    const float* x        = (const float*)d_in[0];
    const float* n1g      = (const float*)d_in[1];
    const float* n1b      = (const float*)d_in[2];
    const float* n2g      = (const float*)d_in[3];
    const float* n2b      = (const float*)d_in[4];
    const float* qkv_w    = (const float*)d_in[5];
    const float* wproj_w  = (const float*)d_in[6];
    const float* rpe      = (const float*)d_in[7];
    const float* ocaq_w   = (const float*)d_in[8];
    const float* ocakv_w  = (const float*)d_in[9];
    const float* ocaproj_w= (const float*)d_in[10];
    const float* ocang    = (const float*)d_in[11];
    const float* ocanb    = (const float*)d_in[12];
    const float* mlp_w1   = (const float*)d_in[13];
    const float* mlp_w2   = (const float*)d_in[14];
    const float* alpha    = (const float*)d_in[15];
    float* out = (float*)d_out;

    // Aliased workspace layout, total 603,979,776 B = 576 MiB.
    //   R0 xw   [0,        96 MiB)  windowed x (live whole launch)
    //   R1 y    [96 MiB,  192 MiB)  W-MSA branch tokens (live to combine)
    //   R2 big  [192 MiB, 480 MiB)  qkv(288) -> mlp hidden(192) ->
    //                               {kv(192) | oca q(96)} -> oca final(96)
    //   R3 sc   [480 MiB, 576 MiB)  LN outs / wattn out / oattn out
    if (ws_size < 603979776ull) return;   // guard: zeros out -> absmax ~10.9 signal
    char* base = (char*)d_ws;
    u16* xw    = (u16*)(base);
    u16* y     = (u16*)(base + 100663296ull);
    u16* big   = (u16*)(base + 201326592ull);   // qkv / mlp hidden / kv / oca final
    u16* qoca  = (u16*)(base + 402653184ull);   // tail of R2: oca q (96 MiB)
    u16* sc    = (u16*)(base + 503316480ull);

    // ---- W-MSA branch ----
    k_part<<<NWIN, 256, 0, stream>>>(x, xw);
    k_ln<<<NTOK / 4, 256, 0, stream>>>(xw, n1g, n1b, sc);
    k_gemm<0><<<dim3(NTOK / 64, 9), 256, 0, stream>>>(sc, qkv_w, big, nullptr, NTOK, 576, 192);
    k_wattn<<<NWIN * 8, 64, 0, stream>>>(big, rpe, sc);
    k_gemm<0><<<dim3(NTOK / 64, 3), 256, 0, stream>>>(sc, wproj_w, y, xw, NTOK, 192, 192);
    // ---- MLP ----
    k_ln<<<NTOK / 4, 256, 0, stream>>>(y, n2g, n2b, sc);
    k_gemm<0><<<dim3(NTOK / 64, 6), 256, 0, stream>>>(sc, mlp_w1, big, nullptr, NTOK, 384, 192);
    k_gelu<<<8192, 256, 0, stream>>>(big, 12582912LL);
    k_gemm<0><<<dim3(NTOK / 64, 3), 256, 0, stream>>>(big, mlp_w2, y, y, NTOK, 192, 384);
    // ---- OCA branch ----
    k_ln<<<NTOK / 4, 256, 0, stream>>>(xw, ocang, ocanb, sc);
    k_gemm<0><<<dim3(NTOK / 64, 3), 256, 0, stream>>>(sc, ocaq_w, qoca, nullptr, NTOK, 192, 192);
    k_gemm<1><<<dim3(NTOK / 64, 6), 256, 0, stream>>>(x, ocakv_w, big, nullptr, NTOK, 384, 192);
    k_oattn<<<NWIN * 8, 64, 0, stream>>>(qoca, big, sc);
    k_gemm<0><<<dim3(NTOK / 64, 3), 256, 0, stream>>>(sc, ocaproj_w, big, xw, NTOK, 192, 192);
    // ---- blend ----
    k_combine<<<8192, 256, 0, stream>>>(x, y, big, alpha, out);
}

// Round 5
// 4191.678 us; speedup vs baseline: 1.6815x; 1.6815x over previous
//
#include <hip/hip_runtime.h>
#include <hip/hip_bf16.h>

// ---------------------------------------------------------------------------
// HAT block: window MSA (+RPE) -> MLP -> overlapping cross-attention -> blend
// B=4, C=192, H=W=256, WS=8, OV=2, NH=8, HD=24
// Round 5: MFMA bf16 GEMMs (64x96 tile, 16x16x32), GELU fused into mlp1,
//          4-wave flash-merge attention kernels (occupancy fix).
// ---------------------------------------------------------------------------

#define NWIN   4096
#define NTOK   262144
#define SCALEA 0.20412414523193154f   // 24^-0.5

typedef unsigned short u16;
typedef unsigned int   u32;
typedef __attribute__((ext_vector_type(8))) short bf16x8;
typedef __attribute__((ext_vector_type(4))) float f32x4;

static __device__ __forceinline__ float bfbits(u32 v) {
    return __uint_as_float(v << 16);
}
static __device__ __forceinline__ u16 fbits(float f) {
    __hip_bfloat16 h = __float2bfloat16(f);   // RNE
    return *reinterpret_cast<u16*>(&h);
}
static __device__ __forceinline__ u32 pack2(float a, float b) {
    return (u32)fbits(a) | ((u32)fbits(b) << 16);
}
static __device__ __forceinline__ void unpack8(uint4 u, float* d) {
    d[0] = bfbits(u.x & 0xffff); d[1] = bfbits(u.x >> 16);
    d[2] = bfbits(u.y & 0xffff); d[3] = bfbits(u.y >> 16);
    d[4] = bfbits(u.z & 0xffff); d[5] = bfbits(u.z >> 16);
    d[6] = bfbits(u.w & 0xffff); d[7] = bfbits(u.w >> 16);
}

// ---- partition: x (B,C,H,W) fp32 -> xw (win, n, c) bf16 --------------------
__global__ __launch_bounds__(256) void k_part(const float* __restrict__ x,
                                              u16* __restrict__ xw) {
    __shared__ float tile[192][65];
    int win = blockIdx.x;
    int b = win >> 10, wh = (win >> 5) & 31, ww = win & 31;
    int t = threadIdx.x;
    const float* xb = x + (size_t)b * 192 * 65536 + (size_t)(wh * 8) * 256 + ww * 8;
    for (int id = t; id < 12288; id += 256) {
        int c = id >> 6, pix = id & 63;
        tile[c][pix] = xb[(size_t)c * 65536 + (pix >> 3) * 256 + (pix & 7)];
    }
    __syncthreads();
    u16* ow = xw + (size_t)win * 12288;
    for (int id = t; id < 12288; id += 256) {
        int n = id / 192, c = id - n * 192;
        ow[id] = fbits(tile[c][n]);
    }
}

// ---- LayerNorm over 192 channels (bf16 in/out, fp32 math) ------------------
__global__ __launch_bounds__(256) void k_ln(const u16* __restrict__ in,
                                            const float* __restrict__ g,
                                            const float* __restrict__ bb,
                                            u16* __restrict__ out) {
    int wid = threadIdx.x >> 6, lane = threadIdx.x & 63;
    size_t tok = (size_t)blockIdx.x * 4 + wid;
    const u16* p = in + tok * 192;
    float x0 = bfbits(p[lane]), x1 = bfbits(p[lane + 64]), x2 = bfbits(p[lane + 128]);
    float s  = x0 + x1 + x2;
    float s2 = x0 * x0 + x1 * x1 + x2 * x2;
#pragma unroll
    for (int off = 32; off; off >>= 1) {
        s  += __shfl_xor(s, off);
        s2 += __shfl_xor(s2, off);
    }
    float mean = s * (1.f / 192.f);
    float var  = s2 * (1.f / 192.f) - mean * mean;
    float rstd = rsqrtf(var + 1e-5f);
    u16* o = out + tok * 192;
    o[lane]       = fbits((x0 - mean) * rstd * g[lane]       + bb[lane]);
    o[lane + 64]  = fbits((x1 - mean) * rstd * g[lane + 64]  + bb[lane + 64]);
    o[lane + 128] = fbits((x2 - mean) * rstd * g[lane + 128] + bb[lane + 128]);
}

// ---- MFMA GEMM: C(MxN) bf16 = A(MxK)bf16 @ B(KxN)fp32->bf16 [+Res][GELU] ---
// BM=64, BN=96, BK=32; 256 threads = 4 waves (2x2), wave tile 32x48 (2x3 frags
// of 16x16x32). A row-major bf16 (or gathered fp32 x, channel-strided).
// Fragment convention (m89-verified): a/b lane l -> row/col = l&15,
// k = (l>>4)*8 + j ; C/D lane l reg i -> row=(l>>4)*4+i, col=l&15.
template <int GATHER, int ACT>
__global__ __launch_bounds__(256) void k_mgemm(const void* __restrict__ Av,
                                               const float* __restrict__ Bw,
                                               u16* __restrict__ C,
                                               const u16* __restrict__ Res,
                                               int M, int N, int K) {
    __shared__ u16 As[64][40];    // +8 pad: 80B row stride -> 2-way max on b128
    __shared__ u16 Bts[96][40];   // B transposed: [col][k]
    int m0 = blockIdx.x << 6, n0 = blockIdx.y * 96;
    int t = threadIdx.x;
    int lane = t & 63, w = t >> 6;
    int wr = w >> 1, wc = w & 1;
    int lr = lane & 15, lg = lane >> 4;

    f32x4 acc[2][3];
#pragma unroll
    for (int q = 0; q < 2; ++q)
#pragma unroll
        for (int p = 0; p < 3; ++p)
            acc[q][p] = (f32x4){0.f, 0.f, 0.f, 0.f};

    const u16*   Ab = (const u16*)Av;
    const float* Af = (const float*)Av;
    long long gbase = 0;
    if (GATHER) {
        int m = m0 + (t & 63);
        gbase = (long long)(m >> 16) * 12582912 + (m & 65535);
    }

    for (int k0 = 0; k0 < K; k0 += 32) {
        // ---- stage A tile [64][32] ----
        if (!GATHER) {
            int r = t >> 2, kc = t & 3;
            uint4 a = *(const uint4*)(Ab + (size_t)(m0 + r) * K + k0 + kc * 8);
            *(uint4*)&As[r][kc * 8] = a;
        } else {
            int r = t & 63, kc = t >> 6;
            float f[8];
#pragma unroll
            for (int j = 0; j < 8; ++j)
                f[j] = Af[gbase + (size_t)(k0 + kc * 8 + j) * 65536];
            uint4 a;
            a.x = pack2(f[0], f[1]); a.y = pack2(f[2], f[3]);
            a.z = pack2(f[4], f[5]); a.w = pack2(f[6], f[7]);
            *(uint4*)&As[r][kc * 8] = a;
        }
        // ---- stage B^T tile [96][32] (fp32 weights, L2-hot, scalar reads) --
        for (int idx = t; idx < 384; idx += 256) {
            int c = idx >> 2, kc = idx & 3;
            float f[8];
#pragma unroll
            for (int j = 0; j < 8; ++j)
                f[j] = Bw[(size_t)(k0 + kc * 8 + j) * N + n0 + c];
            uint4 b;
            b.x = pack2(f[0], f[1]); b.y = pack2(f[2], f[3]);
            b.z = pack2(f[4], f[5]); b.w = pack2(f[6], f[7]);
            *(uint4*)&Bts[c][kc * 8] = b;
        }
        __syncthreads();
        bf16x8 af[2], bfr[3];
#pragma unroll
        for (int q = 0; q < 2; ++q)
            af[q] = *(const bf16x8*)&As[wr * 32 + q * 16 + lr][lg * 8];
#pragma unroll
        for (int p = 0; p < 3; ++p)
            bfr[p] = *(const bf16x8*)&Bts[wc * 48 + p * 16 + lr][lg * 8];
#pragma unroll
        for (int q = 0; q < 2; ++q)
#pragma unroll
            for (int p = 0; p < 3; ++p)
                acc[q][p] = __builtin_amdgcn_mfma_f32_16x16x32_bf16(
                    af[q], bfr[p], acc[q][p], 0, 0, 0);
        __syncthreads();
    }

    // ---- epilogue: residual + optional GELU + bf16 store ----
#pragma unroll
    for (int q = 0; q < 2; ++q) {
        int rowb = m0 + wr * 32 + q * 16 + lg * 4;
#pragma unroll
        for (int p = 0; p < 3; ++p) {
            int col = n0 + wc * 48 + p * 16 + lr;
#pragma unroll
            for (int i = 0; i < 4; ++i) {
                float v = acc[q][p][i];
                size_t off = (size_t)(rowb + i) * N + col;
                if (Res) v += bfbits(Res[off]);
                if (ACT) v = 0.5f * v * (1.f + erff(v * 0.70710678118654752f));
                C[off] = fbits(v);
            }
        }
    }
}

// ---- W-MSA attention: block = (window, head), 4 waves x 16 tokens + merge --
__global__ __launch_bounds__(256) void k_wattn(const u16* __restrict__ qkv,
                                               const float* __restrict__ rpe,
                                               u16* __restrict__ out) {
    __shared__ float sm[3584];          // ks[64*24] | vs[64*24] | rpes[225]
    float* ks   = sm;                   // merge reuse: pm[256] pl[256] po(u16)
    float* vs   = sm + 1536;
    float* rpes = sm + 3072;            // 3072..3297 (< 3584)
    int win = blockIdx.x >> 3, head = blockIdx.x & 7;
    int t = threadIdx.x, lane = t & 63, w = t >> 6;

    for (int idx = t; idx < 512; idx += 256) {
        int j = idx >> 3, c = idx & 7;
        if (c < 6) {
            int off = (c < 3) ? 192 + c * 8 : 384 + (c - 3) * 8;
            uint4 u = *(const uint4*)(qkv + ((size_t)win * 64 + j) * 576 + head * 24 + off);
            float d[8]; unpack8(u, d);
            float* dst = (c < 3) ? ks + j * 24 + c * 8 : vs + j * 24 + (c - 3) * 8;
            *(float4*)dst = *(float4*)d;
            *(float4*)(dst + 4) = *(float4*)(d + 4);
        }
    }
    if (t < 225) rpes[t] = rpe[t * 8 + head];

    float q[24];
    {
        const u16* qp = qkv + ((size_t)win * 64 + lane) * 576 + head * 24;
        unpack8(*(const uint4*)(qp + 0),  q + 0);
        unpack8(*(const uint4*)(qp + 8),  q + 8);
        unpack8(*(const uint4*)(qp + 16), q + 16);
    }
    __syncthreads();

    int my = lane >> 3, mx = lane & 7;
    float m = -1e30f, l = 0.f, o[24] = {};
    int j0 = w * 16;
    for (int jj = 0; jj < 16; ++jj) {
        int j = j0 + jj;
        const float4* kr = (const float4*)(ks + j * 24);
        float a0 = 0.f, a1 = 0.f, a2 = 0.f, a3 = 0.f;
#pragma unroll
        for (int u = 0; u < 6; ++u) {
            float4 k4 = kr[u];
            a0 = fmaf(q[u * 4 + 0], k4.x, a0);
            a1 = fmaf(q[u * 4 + 1], k4.y, a1);
            a2 = fmaf(q[u * 4 + 2], k4.z, a2);
            a3 = fmaf(q[u * 4 + 3], k4.w, a3);
        }
        int jy = j >> 3, jx = j & 7;
        float sv = ((a0 + a1) + (a2 + a3)) * SCALEA
                 + rpes[(my - jy + 7) * 15 + (mx - jx + 7)];
        float mn = fmaxf(m, sv);
        float corr = expf(m - mn);
        float p = expf(sv - mn);
        l = l * corr + p;
        const float4* vr = (const float4*)(vs + j * 24);
#pragma unroll
        for (int u = 0; u < 6; ++u) {
            float4 v4 = vr[u];
            o[u * 4 + 0] = o[u * 4 + 0] * corr + p * v4.x;
            o[u * 4 + 1] = o[u * 4 + 1] * corr + p * v4.y;
            o[u * 4 + 2] = o[u * 4 + 2] * corr + p * v4.z;
            o[u * 4 + 3] = o[u * 4 + 3] * corr + p * v4.w;
        }
        m = mn;
    }

    // ---- flash merge of 4 wave-partials (LDS reused after barrier) ----
    __syncthreads();
    float* pm = sm;
    float* pl = sm + 256;
    u16*   po = (u16*)(sm + 512);
    pm[w * 64 + lane] = m;
    pl[w * 64 + lane] = l;
    {
        u16* pp = po + (w * 64 + lane) * 24;
        uint4 s;
        s.x = pack2(o[0], o[1]);   s.y = pack2(o[2], o[3]);
        s.z = pack2(o[4], o[5]);   s.w = pack2(o[6], o[7]);
        *(uint4*)(pp + 0) = s;
        s.x = pack2(o[8], o[9]);   s.y = pack2(o[10], o[11]);
        s.z = pack2(o[12], o[13]); s.w = pack2(o[14], o[15]);
        *(uint4*)(pp + 8) = s;
        s.x = pack2(o[16], o[17]); s.y = pack2(o[18], o[19]);
        s.z = pack2(o[20], o[21]); s.w = pack2(o[22], o[23]);
        *(uint4*)(pp + 16) = s;
    }
    __syncthreads();
    if (w == 0) {
        float M = fmaxf(fmaxf(pm[lane], pm[64 + lane]),
                        fmaxf(pm[128 + lane], pm[192 + lane]));
        float L = 0.f, O[24] = {};
#pragma unroll
        for (int ww = 0; ww < 4; ++ww) {
            float sc = expf(pm[ww * 64 + lane] - M);
            L += pl[ww * 64 + lane] * sc;
            const u16* pp = po + (ww * 64 + lane) * 24;
#pragma unroll
            for (int d = 0; d < 24; ++d)
                O[d] += bfbits(pp[d]) * sc;
        }
        float inv = 1.f / L;
        u16* op = out + ((size_t)win * 64 + lane) * 192 + head * 24;
        uint4 s;
        s.x = pack2(O[0] * inv, O[1] * inv);   s.y = pack2(O[2] * inv, O[3] * inv);
        s.z = pack2(O[4] * inv, O[5] * inv);   s.w = pack2(O[6] * inv, O[7] * inv);
        *(uint4*)(op + 0) = s;
        s.x = pack2(O[8] * inv, O[9] * inv);   s.y = pack2(O[10] * inv, O[11] * inv);
        s.z = pack2(O[12] * inv, O[13] * inv); s.w = pack2(O[14] * inv, O[15] * inv);
        *(uint4*)(op + 8) = s;
        s.x = pack2(O[16] * inv, O[17] * inv); s.y = pack2(O[18] * inv, O[19] * inv);
        s.z = pack2(O[20] * inv, O[21] * inv); s.w = pack2(O[22] * inv, O[23] * inv);
        *(uint4*)(op + 16) = s;
    }
}

// ---- OCA attention: block = (window, head), 4 waves x 36 tokens + merge ----
__global__ __launch_bounds__(256) void k_oattn(const u16* __restrict__ qb,
                                               const u16* __restrict__ kvp,
                                               u16* __restrict__ out) {
    __shared__ float sm[6912];          // ks[144*24] | vs[144*24]
    float* ks = sm;
    float* vs = sm + 3456;
    int win = blockIdx.x >> 3, head = blockIdx.x & 7;
    int t = threadIdx.x, lane = t & 63, w = t >> 6;
    int b = win >> 10, wh = (win >> 5) & 31, wwn = win & 31;

    for (int idx = t; idx < 1152; idx += 256) {
        int j = idx >> 3, c = idx & 7;
        if (c < 6) {
            int rr = j / 12, cc = j - rr * 12;
            int h = wh * 8 - 2 + rr;  h = h < 0 ? -h : (h > 255 ? 510 - h : h);
            int wp = wwn * 8 - 2 + cc; wp = wp < 0 ? -wp : (wp > 255 ? 510 - wp : wp);
            int off = (c < 3) ? c * 8 : 192 + (c - 3) * 8;
            uint4 u = *(const uint4*)(kvp + ((size_t)(b << 16) + h * 256 + wp) * 384
                                      + head * 24 + off);
            float d[8]; unpack8(u, d);
            float* dst = (c < 3) ? ks + j * 24 + c * 8 : vs + j * 24 + (c - 3) * 8;
            *(float4*)dst = *(float4*)d;
            *(float4*)(dst + 4) = *(float4*)(d + 4);
        }
    }
    float q[24];
    {
        const u16* qp = qb + ((size_t)win * 64 + lane) * 192 + head * 24;
        unpack8(*(const uint4*)(qp + 0),  q + 0);
        unpack8(*(const uint4*)(qp + 8),  q + 8);
        unpack8(*(const uint4*)(qp + 16), q + 16);
    }
    __syncthreads();

    float m = -1e30f, l = 0.f, o[24] = {};
    int j0 = w * 36;
    for (int jj = 0; jj < 36; ++jj) {
        int j = j0 + jj;
        const float4* kr = (const float4*)(ks + j * 24);
        float a0 = 0.f, a1 = 0.f, a2 = 0.f, a3 = 0.f;
#pragma unroll
        for (int u = 0; u < 6; ++u) {
            float4 k4 = kr[u];
            a0 = fmaf(q[u * 4 + 0], k4.x, a0);
            a1 = fmaf(q[u * 4 + 1], k4.y, a1);
            a2 = fmaf(q[u * 4 + 2], k4.z, a2);
            a3 = fmaf(q[u * 4 + 3], k4.w, a3);
        }
        float sv = ((a0 + a1) + (a2 + a3)) * SCALEA;
        float mn = fmaxf(m, sv);
        float corr = expf(m - mn);
        float p = expf(sv - mn);
        l = l * corr + p;
        const float4* vr = (const float4*)(vs + j * 24);
#pragma unroll
        for (int u = 0; u < 6; ++u) {
            float4 v4 = vr[u];
            o[u * 4 + 0] = o[u * 4 + 0] * corr + p * v4.x;
            o[u * 4 + 1] = o[u * 4 + 1] * corr + p * v4.y;
            o[u * 4 + 2] = o[u * 4 + 2] * corr + p * v4.z;
            o[u * 4 + 3] = o[u * 4 + 3] * corr + p * v4.w;
        }
        m = mn;
    }

    __syncthreads();
    float* pm = sm;
    float* pl = sm + 256;
    u16*   po = (u16*)(sm + 512);
    pm[w * 64 + lane] = m;
    pl[w * 64 + lane] = l;
    {
        u16* pp = po + (w * 64 + lane) * 24;
        uint4 s;
        s.x = pack2(o[0], o[1]);   s.y = pack2(o[2], o[3]);
        s.z = pack2(o[4], o[5]);   s.w = pack2(o[6], o[7]);
        *(uint4*)(pp + 0) = s;
        s.x = pack2(o[8], o[9]);   s.y = pack2(o[10], o[11]);
        s.z = pack2(o[12], o[13]); s.w = pack2(o[14], o[15]);
        *(uint4*)(pp + 8) = s;
        s.x = pack2(o[16], o[17]); s.y = pack2(o[18], o[19]);
        s.z = pack2(o[20], o[21]); s.w = pack2(o[22], o[23]);
        *(uint4*)(pp + 16) = s;
    }
    __syncthreads();
    if (w == 0) {
        float M = fmaxf(fmaxf(pm[lane], pm[64 + lane]),
                        fmaxf(pm[128 + lane], pm[192 + lane]));
        float L = 0.f, O[24] = {};
#pragma unroll
        for (int ww = 0; ww < 4; ++ww) {
            float sc = expf(pm[ww * 64 + lane] - M);
            L += pl[ww * 64 + lane] * sc;
            const u16* pp = po + (ww * 64 + lane) * 24;
#pragma unroll
            for (int d = 0; d < 24; ++d)
                O[d] += bfbits(pp[d]) * sc;
        }
        float inv = 1.f / L;
        u16* op = out + ((size_t)win * 64 + lane) * 192 + head * 24;
        uint4 s;
        s.x = pack2(O[0] * inv, O[1] * inv);   s.y = pack2(O[2] * inv, O[3] * inv);
        s.z = pack2(O[4] * inv, O[5] * inv);   s.w = pack2(O[6] * inv, O[7] * inv);
        *(uint4*)(op + 0) = s;
        s.x = pack2(O[8] * inv, O[9] * inv);   s.y = pack2(O[10] * inv, O[11] * inv);
        s.z = pack2(O[12] * inv, O[13] * inv); s.w = pack2(O[14] * inv, O[15] * inv);
        *(uint4*)(op + 8) = s;
        s.x = pack2(O[16] * inv, O[17] * inv); s.y = pack2(O[18] * inv, O[19] * inv);
        s.z = pack2(O[20] * inv, O[21] * inv); s.w = pack2(O[22] * inv, O[23] * inv);
        *(uint4*)(op + 16) = s;
    }
}

// ---- final blend: out = x + a*y_win + (1-a)*oca (reverse partition) --------
__global__ __launch_bounds__(256) void k_combine(const float* __restrict__ x,
                                                 const u16* __restrict__ y,
                                                 const u16* __restrict__ oca,
                                                 const float* __restrict__ alpha_p,
                                                 float* __restrict__ out) {
    float a = alpha_p[0];
    for (size_t idx = (size_t)blockIdx.x * 256 + threadIdx.x; idx < 50331648ull;
         idx += (size_t)gridDim.x * 256) {
        int w = idx & 255;
        int h = (int)(idx >> 8) & 255;
        int bc = (int)(idx >> 16);
        int c = bc % 192, b = bc / 192;
        int win = (b * 32 + (h >> 3)) * 32 + (w >> 3);
        int n = ((h & 7) << 3) + (w & 7);
        size_t off = ((size_t)win * 64 + n) * 192 + c;
        out[idx] = x[idx] + a * bfbits(y[off]) + (1.f - a) * bfbits(oca[off]);
    }
}

// ---------------------------------------------------------------------------
extern "C" void kernel_launch(void* const* d_in, const int* in_sizes, int n_in,
                              void* d_out, int out_size, void* d_ws, size_t ws_size,
                              hipStream_t stream) {
    const float* x        = (const float*)d_in[0];
    const float* n1g      = (const float*)d_in[1];
    const float* n1b      = (const float*)d_in[2];
    const float* n2g      = (const float*)d_in[3];
    const float* n2b      = (const float*)d_in[4];
    const float* qkv_w    = (const float*)d_in[5];
    const float* wproj_w  = (const float*)d_in[6];
    const float* rpe      = (const float*)d_in[7];
    const float* ocaq_w   = (const float*)d_in[8];
    const float* ocakv_w  = (const float*)d_in[9];
    const float* ocaproj_w= (const float*)d_in[10];
    const float* ocang    = (const float*)d_in[11];
    const float* ocanb    = (const float*)d_in[12];
    const float* mlp_w1   = (const float*)d_in[13];
    const float* mlp_w2   = (const float*)d_in[14];
    const float* alpha    = (const float*)d_in[15];
    float* out = (float*)d_out;

    // Aliased workspace, 576 MiB (validated round 4):
    //   R0 xw [0,96M) | R1 y [96M,192M) | R2 big [192M,480M) qkv->hidden->
    //   {kv | ocaq(tail)} -> oca final | R3 sc [480M,576M)
    if (ws_size < 603979776ull) return;
    char* base = (char*)d_ws;
    u16* xw   = (u16*)(base);
    u16* y    = (u16*)(base + 100663296ull);
    u16* big  = (u16*)(base + 201326592ull);
    u16* qoca = (u16*)(base + 402653184ull);
    u16* sc   = (u16*)(base + 503316480ull);

    // ---- W-MSA branch ----
    k_part<<<NWIN, 256, 0, stream>>>(x, xw);
    k_ln<<<NTOK / 4, 256, 0, stream>>>(xw, n1g, n1b, sc);
    k_mgemm<0, 0><<<dim3(NTOK / 64, 6), 256, 0, stream>>>(sc, qkv_w, big, nullptr, NTOK, 576, 192);
    k_wattn<<<NWIN * 8, 256, 0, stream>>>(big, rpe, sc);
    k_mgemm<0, 0><<<dim3(NTOK / 64, 2), 256, 0, stream>>>(sc, wproj_w, y, xw, NTOK, 192, 192);
    // ---- MLP (GELU fused into mlp1 epilogue) ----
    k_ln<<<NTOK / 4, 256, 0, stream>>>(y, n2g, n2b, sc);
    k_mgemm<0, 1><<<dim3(NTOK / 64, 4), 256, 0, stream>>>(sc, mlp_w1, big, nullptr, NTOK, 384, 192);
    k_mgemm<0, 0><<<dim3(NTOK / 64, 2), 256, 0, stream>>>(big, mlp_w2, y, y, NTOK, 192, 384);
    // ---- OCA branch ----
    k_ln<<<NTOK / 4, 256, 0, stream>>>(xw, ocang, ocanb, sc);
    k_mgemm<0, 0><<<dim3(NTOK / 64, 2), 256, 0, stream>>>(sc, ocaq_w, qoca, nullptr, NTOK, 192, 192);
    k_mgemm<1, 0><<<dim3(NTOK / 64, 4), 256, 0, stream>>>(x, ocakv_w, big, nullptr, NTOK, 384, 192);
    k_oattn<<<NWIN * 8, 256, 0, stream>>>(qoca, big, sc);
    k_mgemm<0, 0><<<dim3(NTOK / 64, 2), 256, 0, stream>>>(sc, ocaproj_w, big, xw, NTOK, 192, 192);
    // ---- blend ----
    k_combine<<<8192, 256, 0, stream>>>(x, y, big, alpha, out);
}